// Round 1
// baseline (350.618 us; speedup 1.0000x reference)
//
#include <hip/hip_runtime.h>
#include <math.h>

#define B 16
#define L 512
#define HID 768
#define HEADS 12
#define M 4
#define EMB 768
#define BLK 8
#define NER 6
#define NCLS 97
#define CAT (2*HID + NER)   // 1542
#define EB (EMB*BLK)        // 6144

// ---------------------------------------------------------------------------
// Stage 1: ent_emb = logsumexp over M mention rows.  ent layout: [e][b][d]
// ---------------------------------------------------------------------------
__global__ void k_entemb(const float* __restrict__ seq, const int* __restrict__ epos,
                         float* __restrict__ ent) {
    int b = blockIdx.x, e = blockIdx.y;
    int s0 = epos[(b*2+e)*M + 0] + 1;
    int s1 = epos[(b*2+e)*M + 1] + 1;
    int s2 = epos[(b*2+e)*M + 2] + 1;
    int s3 = epos[(b*2+e)*M + 3] + 1;
    const float* base = seq + (size_t)b*L*HID;
    for (int d = threadIdx.x; d < HID; d += blockDim.x) {
        float v0 = base[(size_t)s0*HID + d];
        float v1 = base[(size_t)s1*HID + d];
        float v2 = base[(size_t)s2*HID + d];
        float v3 = base[(size_t)s3*HID + d];
        float mx = fmaxf(fmaxf(v0, v1), fmaxf(v2, v3));
        float s = expf(v0-mx) + expf(v1-mx) + expf(v2-mx) + expf(v3-mx);
        ent[((size_t)e*B + b)*HID + d] = mx + logf(s);
    }
}

// ---------------------------------------------------------------------------
// Stage 2: ht_att[b][l] = mean_h( mean_m A[b,h,s0m,l] * mean_m A[b,h,s1m,l] )
//          then normalize over l.  One block per batch, one thread per l.
// ---------------------------------------------------------------------------
__global__ void k_htatt(const float* __restrict__ att, const int* __restrict__ epos,
                        float* __restrict__ ht) {
    int b = blockIdx.x;
    int l = threadIdx.x;            // 512 threads
    int s0[M], s1[M];
    for (int m = 0; m < M; ++m) {
        s0[m] = epos[(b*2+0)*M + m] + 1;
        s1[m] = epos[(b*2+1)*M + m] + 1;
    }
    float raw = 0.f;
    for (int h = 0; h < HEADS; ++h) {
        const float* ah = att + ((size_t)b*HEADS + h)*L*L;
        float a0 = 0.f, a1 = 0.f;
        for (int m = 0; m < M; ++m) {
            a0 += ah[(size_t)s0[m]*L + l];
            a1 += ah[(size_t)s1[m]*L + l];
        }
        raw += (a0*0.25f) * (a1*0.25f);
    }
    raw *= (1.0f/HEADS);
    // block-sum over 512 threads
    float v = raw;
    for (int off = 32; off; off >>= 1) v += __shfl_down(v, off);
    __shared__ float warp_s[8];
    __shared__ float tot;
    int wid = threadIdx.x >> 6, lane = threadIdx.x & 63;
    if (lane == 0) warp_s[wid] = v;
    __syncthreads();
    if (threadIdx.x == 0) {
        float t = 0.f;
        for (int i = 0; i < 8; ++i) t += warp_s[i];
        tot = t + 1e-5f;
    }
    __syncthreads();
    ht[b*L + l] = raw / tot;
}

// ---------------------------------------------------------------------------
// Stage 3: rs[b][d] = sum_l seq[b,l,d] * ht[b,l].  Grid (B, HID/128), 128 thr.
// ---------------------------------------------------------------------------
__global__ void k_rs(const float* __restrict__ seq, const float* __restrict__ ht,
                     float* __restrict__ rs) {
    int b = blockIdx.x;
    int d = blockIdx.y*128 + threadIdx.x;
    __shared__ float hl[L];
    for (int l = threadIdx.x; l < L; l += 128) hl[l] = ht[b*L + l];
    __syncthreads();
    const float* sp = seq + (size_t)b*L*HID + d;
    float acc = 0.f;
    for (int l = 0; l < L; ++l) acc += sp[(size_t)l*HID] * hl[l];
    rs[b*HID + d] = acc;
}

// ---------------------------------------------------------------------------
// Stage 4: hs2/ts2 = tanh([ent_e; rs; ner] @ W^T + bias).
// One wave per output row j; each wave accumulates ALL 16 batches so W rows
// are read from HBM exactly once. k-boundaries (768, 1536) are 64-aligned so
// the segment branch is wave-uniform except the 6-lane tail.
// out layout: [t][b][EMB]  (t=0: hs2, t=1: ts2)
// ---------------------------------------------------------------------------
__global__ void k_proj(const float* __restrict__ Wh, const float* __restrict__ bh,
                       const float* __restrict__ Wt, const float* __restrict__ bt,
                       const float* __restrict__ ent, const float* __restrict__ rs,
                       const float* __restrict__ hner, const float* __restrict__ tner,
                       float* __restrict__ out) {
    int t = blockIdx.y;
    int wid = threadIdx.x >> 6, lane = threadIdx.x & 63;
    int j = blockIdx.x*4 + wid;
    const float* W    = t ? Wt : Wh;
    const float* bias = t ? bt : bh;
    const float* e0   = ent + (size_t)t*B*HID;
    const float* ner  = t ? tner : hner;
    const float* wrow = W + (size_t)j*CAT;

    float acc[B];
    for (int b = 0; b < B; ++b) acc[b] = 0.f;

    for (int i = 0; i < 25; ++i) {
        int k = i*64 + lane;
        if (k < CAT) {
            float w = wrow[k];
            if (k < HID) {
                for (int b = 0; b < B; ++b) acc[b] += w * e0[b*HID + k];
            } else if (k < 2*HID) {
                int kk = k - HID;
                for (int b = 0; b < B; ++b) acc[b] += w * rs[b*HID + kk];
            } else {
                int kk = k - 2*HID;
                for (int b = 0; b < B; ++b) acc[b] += w * ner[b*NER + kk];
            }
        }
    }
    for (int off = 32; off; off >>= 1)
        for (int b = 0; b < B; ++b) acc[b] += __shfl_down(acc[b], off);
    if (lane == 0) {
        float bj = bias[j];
        for (int b = 0; b < B; ++b)
            out[((size_t)t*B + b)*EMB + j] = tanhf(acc[b] + bj);
    }
}

// ---------------------------------------------------------------------------
// Stage 5: bl[b, g*64 + i*8 + jj] = hs2[b, g*8+i] * ts2[b, g*8+jj]
// ---------------------------------------------------------------------------
__global__ void k_bl(const float* __restrict__ hs2, const float* __restrict__ ts2,
                     float* __restrict__ bl) {
    int b = blockIdx.x;
    for (int idx = threadIdx.x; idx < EB; idx += blockDim.x) {
        int g = idx >> 6;
        int r = (idx >> 3) & 7;
        int c = idx & 7;
        bl[(size_t)b*EB + idx] = hs2[b*EMB + g*BLK + r] * ts2[b*EMB + g*BLK + c];
    }
}

// ---------------------------------------------------------------------------
// Stage 6: logits[b][c] = bl[b,:] . Wb[c,:] + bb[c].  One block per class;
// Wb read once, bl (393 KB) served from L2 across the 97 blocks.
// ---------------------------------------------------------------------------
__global__ void k_logits(const float* __restrict__ Wb, const float* __restrict__ bb,
                         const float* __restrict__ bl, float* __restrict__ out) {
    int c = blockIdx.x;
    const float* wr = Wb + (size_t)c*EB;
    float acc[B];
    for (int b = 0; b < B; ++b) acc[b] = 0.f;
    for (int k = threadIdx.x; k < EB; k += blockDim.x) {
        float w = wr[k];
        for (int b = 0; b < B; ++b) acc[b] += w * bl[(size_t)b*EB + k];
    }
    int wid = threadIdx.x >> 6, lane = threadIdx.x & 63;
    for (int off = 32; off; off >>= 1)
        for (int b = 0; b < B; ++b) acc[b] += __shfl_down(acc[b], off);
    __shared__ float part[4][B];
    if (lane == 0)
        for (int b = 0; b < B; ++b) part[wid][b] = acc[b];
    __syncthreads();
    if (threadIdx.x < B) {
        int b = threadIdx.x;
        float s = part[0][b] + part[1][b] + part[2][b] + part[3][b];
        out[b*NCLS + c] = s + bb[c];
    }
}

extern "C" void kernel_launch(void* const* d_in, const int* in_sizes, int n_in,
                              void* d_out, int out_size, void* d_ws, size_t ws_size,
                              hipStream_t stream) {
    const float* seq  = (const float*)d_in[0];
    const float* att  = (const float*)d_in[1];
    const int*   epos = (const int*)  d_in[2];
    const float* hner = (const float*)d_in[3];
    const float* tner = (const float*)d_in[4];
    const float* Wh   = (const float*)d_in[5];
    const float* bh   = (const float*)d_in[6];
    const float* Wt   = (const float*)d_in[7];
    const float* bt   = (const float*)d_in[8];
    const float* Wb   = (const float*)d_in[9];
    const float* bb   = (const float*)d_in[10];
    float* out = (float*)d_out;

    // workspace layout (floats): ent[2*B*HID] | rs[B*HID] | ht[B*L] |
    //                            proj[2*B*EMB] | bl[B*EB]   (~672 KB total)
    float* ws   = (float*)d_ws;
    float* ent  = ws;
    float* rs   = ent  + 2*B*HID;
    float* ht   = rs   + B*HID;
    float* proj = ht   + B*L;
    float* bl   = proj + 2*B*EMB;

    k_entemb<<<dim3(B, 2), 256, 0, stream>>>(seq, epos, ent);
    k_htatt <<<dim3(B),   512, 0, stream>>>(att, epos, ht);
    k_rs    <<<dim3(B, HID/128), 128, 0, stream>>>(seq, ht, rs);
    k_proj  <<<dim3(EMB/4, 2), 256, 0, stream>>>(Wh, bh, Wt, bt, ent, rs, hner, tner, proj);
    k_bl    <<<dim3(B),   256, 0, stream>>>(proj, proj + (size_t)B*EMB, bl);
    k_logits<<<dim3(NCLS),256, 0, stream>>>(Wb, bb, bl, out);
}

// Round 2
// 338.335 us; speedup vs baseline: 1.0363x; 1.0363x over previous
//
#include <hip/hip_runtime.h>
#include <math.h>

#define B 16
#define L 512
#define HID 768
#define HEADS 12
#define M 4
#define EMB 768
#define BLK 8
#define NER 6
#define NCLS 97
#define CAT (2*HID + NER)   // 1542
#define EB (EMB*BLK)        // 6144
#define NCH 8               // l-chunks for rs partial sums
#define CATP 1544           // padded CAT for LDS rows

// ---------------------------------------------------------------------------
// K1: per-batch front end — ht_att (attention gather + normalize) and
//     ent_emb (logsumexp over M mentions). One block per batch, 512 threads.
// ---------------------------------------------------------------------------
__global__ void k_front(const float* __restrict__ seq, const float* __restrict__ att,
                        const int* __restrict__ epos,
                        float* __restrict__ ent, float* __restrict__ ht) {
    int b = blockIdx.x;
    __shared__ int ss[2][M];
    if (threadIdx.x < 2*M) {
        int e = threadIdx.x >> 2, m = threadIdx.x & 3;
        ss[e][m] = epos[(b*2+e)*M + m] + 1;
    }
    __syncthreads();

    // --- ht_att: thread = key position l ---
    int l = threadIdx.x;            // 512 threads
    float raw = 0.f;
    for (int h = 0; h < HEADS; ++h) {
        const float* ah = att + ((size_t)b*HEADS + h)*L*L;
        float a0 = 0.f, a1 = 0.f;
        #pragma unroll
        for (int m = 0; m < M; ++m) {
            a0 += ah[(size_t)ss[0][m]*L + l];
            a1 += ah[(size_t)ss[1][m]*L + l];
        }
        raw += a0*a1;
    }
    raw *= (1.f/(M*M*HEADS));
    float v = raw;
    for (int off = 32; off; off >>= 1) v += __shfl_down(v, off);
    __shared__ float wsum[8];
    __shared__ float tot;
    int wid = threadIdx.x >> 6, lane = threadIdx.x & 63;
    if (lane == 0) wsum[wid] = v;
    __syncthreads();
    if (threadIdx.x == 0) {
        float t = 0.f;
        #pragma unroll
        for (int i = 0; i < 8; ++i) t += wsum[i];
        tot = t + 1e-5f;
    }
    __syncthreads();
    ht[b*L + l] = raw / tot;

    // --- ent_emb: 2*HID work items over 512 threads (3 iters) ---
    const float* base = seq + (size_t)b*L*HID;
    for (int idx = threadIdx.x; idx < 2*HID; idx += 512) {
        int e = (idx >= HID) ? 1 : 0;
        int d = idx - e*HID;
        float v0 = base[(size_t)ss[e][0]*HID + d];
        float v1 = base[(size_t)ss[e][1]*HID + d];
        float v2 = base[(size_t)ss[e][2]*HID + d];
        float v3 = base[(size_t)ss[e][3]*HID + d];
        float mx = fmaxf(fmaxf(v0, v1), fmaxf(v2, v3));
        float s = expf(v0-mx) + expf(v1-mx) + expf(v2-mx) + expf(v3-mx);
        ent[((size_t)e*B + b)*HID + d] = mx + logf(s);
    }
}

// ---------------------------------------------------------------------------
// K2: rs partial sums. Grid (B, NCH); block handles 64 l's with float4 loads.
//     part layout: [ch][b][HID]
// ---------------------------------------------------------------------------
__global__ void k_rs_part(const float* __restrict__ seq, const float* __restrict__ ht,
                          float* __restrict__ part) {
    int b = blockIdx.x, ch = blockIdx.y;
    const int LC = L/NCH;           // 64
    __shared__ float hl[L/NCH];
    if (threadIdx.x < LC) hl[threadIdx.x] = ht[b*L + ch*LC + threadIdx.x];
    __syncthreads();
    const float4* sp = (const float4*)(seq + (size_t)b*L*HID + (size_t)ch*LC*HID);
    float4 acc = make_float4(0.f, 0.f, 0.f, 0.f);
    for (int i = 0; i < LC; ++i) {
        float4 vv = sp[i*(HID/4) + threadIdx.x];   // 192 threads cover a row
        float w = hl[i];
        acc.x += vv.x*w; acc.y += vv.y*w; acc.z += vv.z*w; acc.w += vv.w*w;
    }
    ((float4*)(part + ((size_t)ch*B + b)*HID))[threadIdx.x] = acc;
}

// ---------------------------------------------------------------------------
// K3: hs2/ts2 = tanh([ent_e; rs; ner] @ W^T + b). Grid (EMB/8, 2, 2):
//     x = j-chunk (8 j's, one per wave), y = t (h/t), z = batch half.
//     Activations (8 batches x CAT) staged in 48 KB LDS; rs partials reduced
//     during staging. W rows read from HBM once per z (2x total).
// ---------------------------------------------------------------------------
__launch_bounds__(512)
__global__ void k_proj(const float* __restrict__ Wh, const float* __restrict__ bh,
                       const float* __restrict__ Wt, const float* __restrict__ bt,
                       const float* __restrict__ ent, const float* __restrict__ part,
                       const float* __restrict__ hner, const float* __restrict__ tner,
                       float* __restrict__ out) {
    int t = blockIdx.y, zh = blockIdx.z;
    __shared__ float act[8*CATP];   // 49.4 KB
    const float* e0  = ent + (size_t)t*B*HID;
    const float* ner = t ? tner : hner;
    for (int bi = 0; bi < 8; ++bi) {
        int gb = zh*8 + bi;
        for (int k = threadIdx.x; k < CAT; k += 512) {
            float v;
            if (k < HID) {
                v = e0[gb*HID + k];
            } else if (k < 2*HID) {
                int kk = k - HID;
                float s = 0.f;
                #pragma unroll
                for (int c = 0; c < NCH; ++c) s += part[((size_t)c*B + gb)*HID + kk];
                v = s;
            } else {
                v = ner[gb*NER + (k - 2*HID)];
            }
            act[bi*CATP + k] = v;
        }
    }
    __syncthreads();

    int wid = threadIdx.x >> 6, lane = threadIdx.x & 63;
    int j = blockIdx.x*8 + wid;
    const float* wrow = (t ? Wt : Wh) + (size_t)j*CAT;
    float acc[8];
    #pragma unroll
    for (int b = 0; b < 8; ++b) acc[b] = 0.f;
    for (int i = 0; i < 25; ++i) {
        int k = i*64 + lane;
        if (k < CAT) {
            float w = wrow[k];
            #pragma unroll
            for (int b = 0; b < 8; ++b) acc[b] += w * act[b*CATP + k];
        }
    }
    for (int off = 32; off; off >>= 1)
        #pragma unroll
        for (int b = 0; b < 8; ++b) acc[b] += __shfl_down(acc[b], off);
    if (lane == 0) {
        float bj = (t ? bt : bh)[j];
        #pragma unroll
        for (int b = 0; b < 8; ++b)
            out[((size_t)t*B + zh*8 + b)*EMB + j] = tanhf(acc[b] + bj);
    }
}

// ---------------------------------------------------------------------------
// K4: logits[b][c] = sum_k Wb[c,k] * hs2[b,g*8+r] * ts2[b,g*8+cc] + bb[c]
//     (bl fused — never materialized). One block per class, 512 threads.
//     proj (98 KB) is L2-hot across the 97 blocks.
// ---------------------------------------------------------------------------
__launch_bounds__(512)
__global__ void k_logits(const float* __restrict__ Wb, const float* __restrict__ bb,
                         const float* __restrict__ proj, float* __restrict__ out) {
    int c = blockIdx.x;
    const float* wr = Wb + (size_t)c*EB;
    const float* ph = proj;                    // hs2 [b][EMB]
    const float* pt = proj + (size_t)B*EMB;    // ts2 [b][EMB]
    float acc[B];
    #pragma unroll
    for (int b = 0; b < B; ++b) acc[b] = 0.f;
    for (int k = threadIdx.x; k < EB; k += 512) {   // 12 iters
        int g = k >> 6, r = (k >> 3) & 7, cc = k & 7;
        float w = wr[k];
        int o = g*8;
        #pragma unroll
        for (int b = 0; b < B; ++b)
            acc[b] += w * ph[b*EMB + o + r] * pt[b*EMB + o + cc];
    }
    int wid = threadIdx.x >> 6, lane = threadIdx.x & 63;
    for (int off = 32; off; off >>= 1)
        #pragma unroll
        for (int b = 0; b < B; ++b) acc[b] += __shfl_down(acc[b], off);
    __shared__ float partl[8][B];
    if (lane == 0)
        #pragma unroll
        for (int b = 0; b < B; ++b) partl[wid][b] = acc[b];
    __syncthreads();
    if (threadIdx.x < B) {
        int b = threadIdx.x;
        float s = 0.f;
        #pragma unroll
        for (int w = 0; w < 8; ++w) s += partl[w][b];
        out[b*NCLS + c] = s + bb[c];
    }
}

extern "C" void kernel_launch(void* const* d_in, const int* in_sizes, int n_in,
                              void* d_out, int out_size, void* d_ws, size_t ws_size,
                              hipStream_t stream) {
    const float* seq  = (const float*)d_in[0];
    const float* att  = (const float*)d_in[1];
    const int*   epos = (const int*)  d_in[2];
    const float* hner = (const float*)d_in[3];
    const float* tner = (const float*)d_in[4];
    const float* Wh   = (const float*)d_in[5];
    const float* bh   = (const float*)d_in[6];
    const float* Wt   = (const float*)d_in[7];
    const float* bt   = (const float*)d_in[8];
    const float* Wb   = (const float*)d_in[9];
    const float* bb   = (const float*)d_in[10];
    float* out = (float*)d_out;

    // workspace (floats): ent[2*B*HID] | ht[B*L] | part[NCH*B*HID] | proj[2*B*EMB]
    float* ws   = (float*)d_ws;
    float* ent  = ws;
    float* ht   = ent  + 2*B*HID;
    float* part = ht   + B*L;
    float* proj = part + (size_t)NCH*B*HID;

    k_front  <<<dim3(B),          512, 0, stream>>>(seq, att, epos, ent, ht);
    k_rs_part<<<dim3(B, NCH),     192, 0, stream>>>(seq, ht, part);
    k_proj   <<<dim3(EMB/8, 2, 2),512, 0, stream>>>(Wh, bh, Wt, bt, ent, part, hner, tner, proj);
    k_logits <<<dim3(NCLS),       512, 0, stream>>>(Wb, bb, proj, out);
}

// Round 3
// 295.722 us; speedup vs baseline: 1.1856x; 1.1441x over previous
//
#include <hip/hip_runtime.h>
#include <math.h>

#define B 16
#define L 512
#define HID 768
#define HEADS 12
#define M 4
#define EMB 768
#define BLK 8
#define NER 6
#define NCLS 97
#define CAT (2*HID + NER)   // 1542
#define EB (EMB*BLK)        // 6144
#define NCH 8               // l-chunks for rs

// ---------------------------------------------------------------------------
// K1: grid (B, HEADS), 512 thr. Per-head attention partial product
//     pp[b][h][l] = (sum_m A[b,h,s0m,l]) * (sum_m A[b,h,s1m,l])   (unscaled)
//     Side jobs on spare y-blocks: h<2 -> ent_emb (logsumexp, e=h);
//     h==2 -> zero rs for the atomics in K2.
// ---------------------------------------------------------------------------
__global__ void k_att(const float* __restrict__ att, const float* __restrict__ seq,
                      const int* __restrict__ epos,
                      float* __restrict__ pp, float* __restrict__ ent,
                      float* __restrict__ rs) {
    int b = blockIdx.x, h = blockIdx.y;
    __shared__ int ss[2][M];
    if (threadIdx.x < 2*M) {
        int e = threadIdx.x >> 2, m = threadIdx.x & 3;
        ss[e][m] = epos[(b*2+e)*M + m] + 1;
    }
    __syncthreads();

    int l = threadIdx.x;   // 512 threads = L
    const float* ah = att + ((size_t)b*HEADS + h)*L*L;
    float a0 = 0.f, a1 = 0.f;
    #pragma unroll
    for (int m = 0; m < M; ++m) {
        a0 += ah[(size_t)ss[0][m]*L + l];
        a1 += ah[(size_t)ss[1][m]*L + l];
    }
    pp[((size_t)b*HEADS + h)*L + l] = a0*a1;

    if (h < 2) {
        // ent_emb for entity e=h: logsumexp over M mention rows
        const float* base = seq + (size_t)b*L*HID;
        for (int d = threadIdx.x; d < HID; d += 512) {
            float v0 = base[(size_t)ss[h][0]*HID + d];
            float v1 = base[(size_t)ss[h][1]*HID + d];
            float v2 = base[(size_t)ss[h][2]*HID + d];
            float v3 = base[(size_t)ss[h][3]*HID + d];
            float mx = fmaxf(fmaxf(v0, v1), fmaxf(v2, v3));
            float s = expf(v0-mx) + expf(v1-mx) + expf(v2-mx) + expf(v3-mx);
            ent[((size_t)h*B + b)*HID + d] = mx + logf(s);
        }
    } else if (h == 2) {
        for (int d = threadIdx.x; d < HID; d += 512) rs[b*HID + d] = 0.f;
    }
}

// ---------------------------------------------------------------------------
// K2: grid (B, NCH), 192 thr. Recombine per-head partials (L2-hot) into
//     normalized ht weights in LDS, then accumulate rs partials for this
//     block's 64 l's with float4 loads; atomicAdd into rs[b][d].
// ---------------------------------------------------------------------------
__launch_bounds__(192)
__global__ void k_rs(const float* __restrict__ seq, const float* __restrict__ pp,
                     float* __restrict__ rs) {
    int b = blockIdx.x, ch = blockIdx.y;
    __shared__ float sraw[L];
    __shared__ float red[3];
    __shared__ float sinv;
    float psum = 0.f;
    for (int l = threadIdx.x; l < L; l += 192) {
        float r = 0.f;
        #pragma unroll
        for (int h = 0; h < HEADS; ++h) r += pp[((size_t)b*HEADS + h)*L + l];
        r *= (1.f/(M*M*HEADS));
        sraw[l] = r;
        psum += r;
    }
    for (int off = 32; off; off >>= 1) psum += __shfl_down(psum, off);
    int wid = threadIdx.x >> 6, lane = threadIdx.x & 63;
    if (lane == 0) red[wid] = psum;
    __syncthreads();
    if (threadIdx.x == 0) sinv = 1.f/(red[0] + red[1] + red[2] + 1e-5f);
    __syncthreads();
    float inv = sinv;

    const float4* sp = (const float4*)(seq + (size_t)b*L*HID + (size_t)ch*(L/NCH)*HID);
    float4 acc = make_float4(0.f, 0.f, 0.f, 0.f);
    for (int i = 0; i < L/NCH; ++i) {
        float w = sraw[ch*(L/NCH) + i] * inv;
        float4 v = sp[i*(HID/4) + threadIdx.x];
        acc.x += v.x*w; acc.y += v.y*w; acc.z += v.z*w; acc.w += v.w*w;
    }
    float* rp = rs + b*HID + threadIdx.x*4;
    atomicAdd(rp+0, acc.x);
    atomicAdd(rp+1, acc.y);
    atomicAdd(rp+2, acc.z);
    atomicAdd(rp+3, acc.w);
}

// ---------------------------------------------------------------------------
// K3: hs2/ts2 = tanh([ent_e; rs; ner] @ W^T + b). Grid (EMB/8, 2, 2).
//     Activations transposed in LDS as actA/actB[k][4] so the 8-batch inner
//     read is 2 conflict-free ds_read_b128 per k.
// ---------------------------------------------------------------------------
__launch_bounds__(512)
__global__ void k_proj(const float* __restrict__ Wh, const float* __restrict__ bh,
                       const float* __restrict__ Wt, const float* __restrict__ bt,
                       const float* __restrict__ ent, const float* __restrict__ rs,
                       const float* __restrict__ hner, const float* __restrict__ tner,
                       float* __restrict__ out) {
    int t = blockIdx.y, zh = blockIdx.z;
    __shared__ float actA[CAT*4];   // batches zh*8 + 0..3
    __shared__ float actB[CAT*4];   // batches zh*8 + 4..7
    const float* e0  = ent + (size_t)t*B*HID;
    const float* ner = t ? tner : hner;
    for (int idx = threadIdx.x; idx < CAT*8; idx += 512) {
        int k = idx >> 3, bi = idx & 7;
        int gb = zh*8 + bi;
        float v;
        if (k < HID)            v = e0[gb*HID + k];
        else if (k < 2*HID)     v = rs[gb*HID + (k - HID)];
        else                    v = ner[gb*NER + (k - 2*HID)];
        if (bi < 4) actA[k*4 + bi] = v; else actB[k*4 + bi - 4] = v;
    }
    __syncthreads();

    int wid = threadIdx.x >> 6, lane = threadIdx.x & 63;
    int j = blockIdx.x*8 + wid;
    const float* wrow = (t ? Wt : Wh) + (size_t)j*CAT;
    float acc[8];
    #pragma unroll
    for (int b = 0; b < 8; ++b) acc[b] = 0.f;
    for (int i = 0; i < 25; ++i) {
        int k = i*64 + lane;
        if (k < CAT) {
            float w = wrow[k];
            float4 a = *(const float4*)&actA[k*4];
            float4 c = *(const float4*)&actB[k*4];
            acc[0] += w*a.x; acc[1] += w*a.y; acc[2] += w*a.z; acc[3] += w*a.w;
            acc[4] += w*c.x; acc[5] += w*c.y; acc[6] += w*c.z; acc[7] += w*c.w;
        }
    }
    for (int off = 32; off; off >>= 1)
        #pragma unroll
        for (int b = 0; b < 8; ++b) acc[b] += __shfl_down(acc[b], off);
    if (lane == 0) {
        float bj = (t ? bt : bh)[j];
        #pragma unroll
        for (int b = 0; b < 8; ++b)
            out[((size_t)t*B + zh*8 + b)*EMB + j] = tanhf(acc[b] + bj);
    }
}

// ---------------------------------------------------------------------------
// K4: materialize bl[b][k] = hs2[b][g*8+r] * ts2[b][g*8+cc], float4 writes.
// ---------------------------------------------------------------------------
__global__ void k_bl(const float* __restrict__ proj, float* __restrict__ bl) {
    int b = blockIdx.x;
    const float* ph = proj + (size_t)b*EMB;
    const float* pt = proj + (size_t)B*EMB + (size_t)b*EMB;
    for (int i4 = threadIdx.x; i4 < EB/4; i4 += 512) {
        int k = i4*4;
        int g = k >> 6, r = (k >> 3) & 7, c0 = k & 7;   // c0 in {0,4}
        float pr = ph[g*8 + r];
        float4 q = *(const float4*)(pt + g*8 + c0);
        float4 o = make_float4(pr*q.x, pr*q.y, pr*q.z, pr*q.w);
        ((float4*)(bl + (size_t)b*EB))[i4] = o;
    }
}

// ---------------------------------------------------------------------------
// K5: logits = bl @ Wb^T + bb. One block per class, pure float4 dot,
//     all 16 batches in registers (Wb read once from HBM; bl L2-hot).
// ---------------------------------------------------------------------------
__launch_bounds__(512)
__global__ void k_logits(const float* __restrict__ Wb, const float* __restrict__ bb,
                         const float* __restrict__ bl, float* __restrict__ out) {
    int c = blockIdx.x;
    const float4* wr = (const float4*)(Wb + (size_t)c*EB);
    float acc[B];
    #pragma unroll
    for (int b = 0; b < B; ++b) acc[b] = 0.f;
    for (int i = threadIdx.x; i < EB/4; i += 512) {   // 3 iters
        float4 w = wr[i];
        #pragma unroll
        for (int b = 0; b < B; ++b) {
            float4 v = ((const float4*)(bl + (size_t)b*EB))[i];
            acc[b] += w.x*v.x + w.y*v.y + w.z*v.z + w.w*v.w;
        }
    }
    int wid = threadIdx.x >> 6, lane = threadIdx.x & 63;
    for (int off = 32; off; off >>= 1)
        #pragma unroll
        for (int b = 0; b < B; ++b) acc[b] += __shfl_down(acc[b], off);
    __shared__ float partl[8][B];
    if (lane == 0)
        #pragma unroll
        for (int b = 0; b < B; ++b) partl[wid][b] = acc[b];
    __syncthreads();
    if (threadIdx.x < B) {
        int b = threadIdx.x;
        float s = 0.f;
        #pragma unroll
        for (int w = 0; w < 8; ++w) s += partl[w][b];
        out[b*NCLS + c] = s + bb[c];
    }
}

extern "C" void kernel_launch(void* const* d_in, const int* in_sizes, int n_in,
                              void* d_out, int out_size, void* d_ws, size_t ws_size,
                              hipStream_t stream) {
    const float* seq  = (const float*)d_in[0];
    const float* att  = (const float*)d_in[1];
    const int*   epos = (const int*)  d_in[2];
    const float* hner = (const float*)d_in[3];
    const float* tner = (const float*)d_in[4];
    const float* Wh   = (const float*)d_in[5];
    const float* bh   = (const float*)d_in[6];
    const float* Wt   = (const float*)d_in[7];
    const float* bt   = (const float*)d_in[8];
    const float* Wb   = (const float*)d_in[9];
    const float* bb   = (const float*)d_in[10];
    float* out = (float*)d_out;

    // ws (floats): pp[B*HEADS*L] | ent[2*B*HID] | rs[B*HID] | proj[2*B*EMB] | bl[B*EB]
    float* ws   = (float*)d_ws;
    float* pp   = ws;
    float* ent  = pp   + (size_t)B*HEADS*L;
    float* rs   = ent  + 2*B*HID;
    float* proj = rs   + B*HID;
    float* bl   = proj + 2*B*EMB;

    k_att   <<<dim3(B, HEADS), 512, 0, stream>>>(att, seq, epos, pp, ent, rs);
    k_rs    <<<dim3(B, NCH),   192, 0, stream>>>(seq, pp, rs);
    k_proj  <<<dim3(EMB/8, 2, 2), 512, 0, stream>>>(Wh, bh, Wt, bt, ent, rs, hner, tner, proj);
    k_bl    <<<dim3(B),        512, 0, stream>>>(proj, bl);
    k_logits<<<dim3(NCLS),     512, 0, stream>>>(Wb, bb, bl, out);
}